// Round 1
// 670.200 us; speedup vs baseline: 1.0006x; 1.0006x over previous
//
#include <hip/hip_runtime.h>
#include <hip/hip_bf16.h>
#include <math.h>

#define HID 128
#define K1  288         // padded K for layer 1 (268 -> 9*32)
#define Z1S 136         // S LDS stride in bf16 (272 B rows, b128-aligned)
#define SMS 136         // sage_pq h-transpose LDS stride in bf16

typedef __attribute__((ext_vector_type(8))) short short8;   // 8 bf16 = 4 VGPRs
typedef __attribute__((ext_vector_type(4))) float floatx4;  // MFMA accumulator

// HW packed convert: v_cvt_pk_bf16_f32 (RNE), lo -> low 16 bits
static __device__ __forceinline__ unsigned pack2bf(float lo, float hi) {
    __hip_bfloat162 v = __float22bfloat162_rn(float2{lo, hi});
    union { __hip_bfloat162 b; unsigned u; } cv; cv.b = v; return cv.u;
}
static __device__ __forceinline__ unsigned short f2bf16(float v) {
    return (unsigned short)pack2bf(v, v);
}
static __device__ __forceinline__ float bf2f_lo(unsigned u) { return __uint_as_float(u << 16); }
static __device__ __forceinline__ float bf2f_hi(unsigned u) { return __uint_as_float(u & 0xffff0000u); }

// ---------- CSR build ----------
__global__ void hist_kernel(const int* __restrict__ dst, unsigned* __restrict__ deg, int E) {
    int e = blockIdx.x * 256 + threadIdx.x;
    if (e < E) atomicAdd(&deg[dst[e]], 1u);
}

__global__ __launch_bounds__(256) void scan_partial(const unsigned* __restrict__ deg,
        unsigned* __restrict__ off, unsigned* __restrict__ bsum, int N) {
    int t = threadIdx.x;
    int base = blockIdx.x * 2048 + t * 8;
    unsigned v[8]; unsigned run = 0;
#pragma unroll
    for (int i = 0; i < 8; i++) {
        int g = base + i;
        unsigned d = (g < N) ? deg[g] : 0u;
        v[i] = run; run += d;
    }
    __shared__ unsigned s[256];
    s[t] = run; __syncthreads();
    for (int o2 = 1; o2 < 256; o2 <<= 1) {
        unsigned x = (t >= o2) ? s[t - o2] : 0u;
        __syncthreads();
        s[t] += x;
        __syncthreads();
    }
    unsigned texcl = (t > 0) ? s[t - 1] : 0u;
    if (t == 255) bsum[blockIdx.x] = s[255];
#pragma unroll
    for (int i = 0; i < 8; i++) {
        int g = base + i;
        if (g < N) off[g] = texcl + v[i];
    }
}

__global__ void scan_bsum(unsigned* bsum, int B) {   // B <= 64, single wave inclusive
    int t = threadIdx.x;
    unsigned v = (t < B) ? bsum[t] : 0u;
    for (int o = 1; o < 64; o <<= 1) {
        unsigned x = __shfl_up(v, o);
        if (t >= o) v += x;
    }
    if (t < B) bsum[t] = v;
}

__global__ void scan_add(unsigned* __restrict__ off, const unsigned* __restrict__ bsum,
                         unsigned* __restrict__ cur, int N) {
    int g = blockIdx.x * 256 + threadIdx.x;
    if (g >= N) return;
    cur[g] = 0u;                 // folded curp reset (one fewer memset dispatch)
    int blk = g >> 11;
    if (blk > 0) off[g] += bsum[blk - 1];
}

// fills: csrS/csrD/csrE + eattr copied into CSR order as bf16 (24 B/edge)
__global__ void csr_fill(const int* __restrict__ src, const int* __restrict__ dst,
                         const float* __restrict__ eattr,
                         const unsigned* __restrict__ off, unsigned* __restrict__ cur,
                         int* __restrict__ csrS, int* __restrict__ csrD,
                         int* __restrict__ csrE, unsigned short* __restrict__ eattrP, int E) {
    int e = blockIdx.x * 256 + threadIdx.x;
    if (e >= E) return;
    int d = dst[e];
    unsigned p = off[d] + atomicAdd(&cur[d], 1u);
    csrS[p] = src[e];
    csrD[p] = d;
    csrE[p] = e;
    const float* ep = eattr + (size_t)e * 12;       // 48 B, 16-aligned: coalesced read
    float4 v0 = *(const float4*)ep;
    float4 v1 = *(const float4*)(ep + 4);
    float4 v2 = *(const float4*)(ep + 8);
    unsigned* op = (unsigned*)(eattrP + (size_t)p * 12);  // 4-aligned scatter write
    op[0] = pack2bf(v0.x, v0.y); op[1] = pack2bf(v0.z, v0.w);
    op[2] = pack2bf(v1.x, v1.y); op[3] = pack2bf(v1.z, v1.w);
    op[4] = pack2bf(v2.x, v2.y); op[5] = pack2bf(v2.z, v2.w);
}

// ---------- node projection (writes bf16 h) ----------
__global__ void node_proj_kernel(const float* __restrict__ x, const float* __restrict__ W,
                                 const float* __restrict__ b, unsigned short* __restrict__ hbf, int N) {
    int i = blockIdx.x * 256 + threadIdx.x;   // over N*64, 2 cols/thread
    if (i >= N * 64) return;
    int n = i >> 6, f2 = (i & 63) * 2;
    float a0 = b[f2], a1 = b[f2 + 1];
#pragma unroll
    for (int k = 0; k < 5; k++) {
        float xv = x[n * 5 + k];
        a0 = fmaf(xv, W[k * HID + f2], a0);
        a1 = fmaf(xv, W[k * HID + f2 + 1], a1);
    }
    *(unsigned*)&hbf[(size_t)n * HID + f2] = pack2bf(a0, a1);
}

// ---------- merged weight prep ----------
__global__ void prep_weights(const float* __restrict__ W1, const float* __restrict__ W2,
                             const float* __restrict__ Wl, const float* __restrict__ Wr,
                             unsigned short* __restrict__ W1T, unsigned short* __restrict__ W2T,
                             unsigned short* __restrict__ WST) {
    int i = blockIdx.x * 256 + threadIdx.x;
    if (i < 128 * K1) {
        int n = i / K1, k = i - n * K1;
        W1T[i] = (k < 268) ? f2bf16(W1[k * HID + n]) : (unsigned short)0;
        return;
    }
    int j = i - 128 * K1;
    if (j < 64 * HID) {
        int n = j >> 7, k = j & 127;
        W2T[j] = f2bf16(W2[k * 64 + n]);
        return;
    }
    int m = j - 64 * HID;
    if (m < 3 * 128 * 256) {
        int l = m >> 15, rem = m & 32767, n = rem >> 8, k = rem & 255;
        float v = (k < 128) ? Wl[l * 16384 + k * 128 + n] : Wr[l * 16384 + (k - 128) * 128 + n];
        WST[m] = f2bf16(v);
    }
}

// ---------- mean aggregation: 4 nodes per wave, 8 rows in flight per group ----------
__global__ __launch_bounds__(256) void agg_csr(const unsigned short* __restrict__ hbf,
        const int* __restrict__ csr, const unsigned* __restrict__ off,
        const unsigned* __restrict__ degu, unsigned short* __restrict__ mean_bf, int N) {
    const int wv = threadIdx.x >> 6, lane = threadIdx.x & 63;
    const int g = lane >> 4, c = lane & 15;
    const int n = (blockIdx.x * 4 + wv) * 4 + g;
    const int nc = n < N ? n : N - 1;
    const unsigned o = off[nc];
    const unsigned d = (n < N) ? degu[nc] : 0u;
    unsigned dmax = d;
    dmax = max(dmax, (unsigned)__shfl_xor((int)dmax, 16));
    dmax = max(dmax, (unsigned)__shfl_xor((int)dmax, 32));

    float acc[8] = {0.f, 0.f, 0.f, 0.f, 0.f, 0.f, 0.f, 0.f};
    for (unsigned i = 0; i < dmax; i += 8) {
        uint4 v[8];
#pragma unroll
        for (int j = 0; j < 8; j++) {
            unsigned p = (i + j < d) ? o + i + j : 0u;
            int s = csr[p];
            v[j] = *(const uint4*)&hbf[(size_t)s * HID + c * 8];
        }
#pragma unroll
        for (int j = 0; j < 8; j++) {
            if (i + j < d) {
                acc[0] += bf2f_lo(v[j].x); acc[1] += bf2f_hi(v[j].x);
                acc[2] += bf2f_lo(v[j].y); acc[3] += bf2f_hi(v[j].y);
                acc[4] += bf2f_lo(v[j].z); acc[5] += bf2f_hi(v[j].z);
                acc[6] += bf2f_lo(v[j].w); acc[7] += bf2f_hi(v[j].w);
            }
        }
    }
    if (n < N) {
        float inv = d ? 1.f / (float)d : 0.f;
        uint4 p;
        p.x = pack2bf(acc[0] * inv, acc[1] * inv);
        p.y = pack2bf(acc[2] * inv, acc[3] * inv);
        p.z = pack2bf(acc[4] * inv, acc[5] * inv);
        p.w = pack2bf(acc[6] * inv, acc[7] * inv);
        *(uint4*)&mean_bf[(size_t)n * HID + c * 8] = p;
    }
}

// ---------- SAGE layer (layers 0,1): h in-place, no LDS ----------
__global__ __launch_bounds__(256) void sage_mfma(
    unsigned short* __restrict__ hbf, const unsigned short* __restrict__ mean_bf,
    const unsigned short* __restrict__ WT,
    const float* __restrict__ bl, const float* __restrict__ g,
    const float* __restrict__ bet, int N) {
    const int t = threadIdx.x, wave = t >> 6, lane = t & 63;
    const int ln15 = lane & 15, quad = lane >> 4;
    const int blkBase = blockIdx.x * 128;

    short8 af[2][8];
#pragma unroll
    for (int tt = 0; tt < 2; tt++) {
        int m = blkBase + tt * 64 + wave * 16 + ln15;
        int mc = m < N ? m : N - 1;
#pragma unroll
        for (int kt = 0; kt < 4; kt++)
            af[tt][kt] = *(const short8*)&mean_bf[(size_t)mc * HID + kt * 32 + quad * 8];
#pragma unroll
        for (int kt = 0; kt < 4; kt++)
            af[tt][4 + kt] = *(const short8*)&hbf[(size_t)mc * HID + kt * 32 + quad * 8];
    }

    floatx4 acc[2][8];
#pragma unroll
    for (int nt = 0; nt < 8; nt++) {
        floatx4 a0 = {0.f, 0.f, 0.f, 0.f}, a1 = {0.f, 0.f, 0.f, 0.f};
#pragma unroll
        for (int kt = 0; kt < 8; kt++) {
            short8 b = *(const short8*)&WT[(nt * 16 + ln15) * 256 + kt * 32 + quad * 8];
            a0 = __builtin_amdgcn_mfma_f32_16x16x32_bf16(af[0][kt], b, a0, 0, 0, 0);
            a1 = __builtin_amdgcn_mfma_f32_16x16x32_bf16(af[1][kt], b, a1, 0, 0, 0);
        }
        acc[0][nt] = a0; acc[1][nt] = a1;
    }

    float blv[8], gv[8], bv[8];
#pragma unroll
    for (int nt = 0; nt < 8; nt++) {
        int col = nt * 16 + ln15;
        blv[nt] = bl[col]; gv[nt] = g[col]; bv[nt] = bet[col];
    }

#pragma unroll
    for (int tt = 0; tt < 2; tt++) {
#pragma unroll
        for (int r = 0; r < 4; r++) {
            float s = 0.f;
#pragma unroll
            for (int nt = 0; nt < 8; nt++) s += acc[tt][nt][r] + blv[nt];
            s += __shfl_xor(s, 1); s += __shfl_xor(s, 2);
            s += __shfl_xor(s, 4); s += __shfl_xor(s, 8);
            float mu = s * (1.f / 128.f);
            float q = 0.f;
#pragma unroll
            for (int nt = 0; nt < 8; nt++) { float c = acc[tt][nt][r] + blv[nt] - mu; q += c * c; }
            q += __shfl_xor(q, 1); q += __shfl_xor(q, 2);
            q += __shfl_xor(q, 4); q += __shfl_xor(q, 8);
            float rstd = rsqrtf(q * (1.f / 128.f) + 1e-5f);
            int node = blkBase + tt * 64 + wave * 16 + quad * 4 + r;
            if (node < N) {
#pragma unroll
                for (int nt = 0; nt < 8; nt++) {
                    float y = fmaxf((acc[tt][nt][r] + blv[nt] - mu) * rstd * gv[nt] + bv[nt], 0.f);
                    hbf[(size_t)node * HID + nt * 16 + ln15] = f2bf16(y);
                }
            }
        }
    }
}

// ---------- SAGE final layer + P/Q epilogue: writes P (over hbf) and Q (over meanbf) ----------
__global__ __launch_bounds__(256) void sage_pq_mfma(
    unsigned short* __restrict__ hbf, unsigned short* __restrict__ mean_bf,
    const unsigned short* __restrict__ WT,
    const float* __restrict__ bl, const float* __restrict__ g,
    const float* __restrict__ bet, const unsigned short* __restrict__ W1T, int N) {
    __shared__ __align__(16) unsigned short sh[128 * SMS];   // 34816 B h-transpose
    const int t = threadIdx.x, wave = t >> 6, lane = t & 63;
    const int ln15 = lane & 15, quad = lane >> 4;
    const int blkBase = blockIdx.x * 128;

    short8 af[2][8];
#pragma unroll
    for (int tt = 0; tt < 2; tt++) {
        int m = blkBase + tt * 64 + wave * 16 + ln15;
        int mc = m < N ? m : N - 1;
#pragma unroll
        for (int kt = 0; kt < 4; kt++)
            af[tt][kt] = *(const short8*)&mean_bf[(size_t)mc * HID + kt * 32 + quad * 8];
#pragma unroll
        for (int kt = 0; kt < 4; kt++)
            af[tt][4 + kt] = *(const short8*)&hbf[(size_t)mc * HID + kt * 32 + quad * 8];
    }

    floatx4 acc[2][8];
#pragma unroll
    for (int nt = 0; nt < 8; nt++) {
        floatx4 a0 = {0.f, 0.f, 0.f, 0.f}, a1 = {0.f, 0.f, 0.f, 0.f};
#pragma unroll
        for (int kt = 0; kt < 8; kt++) {
            short8 b = *(const short8*)&WT[(nt * 16 + ln15) * 256 + kt * 32 + quad * 8];
            a0 = __builtin_amdgcn_mfma_f32_16x16x32_bf16(af[0][kt], b, a0, 0, 0, 0);
            a1 = __builtin_amdgcn_mfma_f32_16x16x32_bf16(af[1][kt], b, a1, 0, 0, 0);
        }
        acc[0][nt] = a0; acc[1][nt] = a1;
    }

    float blv[8], gv[8], bv[8];
#pragma unroll
    for (int nt = 0; nt < 8; nt++) {
        int col = nt * 16 + ln15;
        blv[nt] = bl[col]; gv[nt] = g[col]; bv[nt] = bet[col];
    }

    // LN + ReLU -> LDS transpose (write all 128 rows; clamped rows harmless, discarded on store)
#pragma unroll
    for (int tt = 0; tt < 2; tt++) {
#pragma unroll
        for (int r = 0; r < 4; r++) {
            float s = 0.f;
#pragma unroll
            for (int nt = 0; nt < 8; nt++) s += acc[tt][nt][r] + blv[nt];
            s += __shfl_xor(s, 1); s += __shfl_xor(s, 2);
            s += __shfl_xor(s, 4); s += __shfl_xor(s, 8);
            float mu = s * (1.f / 128.f);
            float q = 0.f;
#pragma unroll
            for (int nt = 0; nt < 8; nt++) { float c = acc[tt][nt][r] + blv[nt] - mu; q += c * c; }
            q += __shfl_xor(q, 1); q += __shfl_xor(q, 2);
            q += __shfl_xor(q, 4); q += __shfl_xor(q, 8);
            float rstd = rsqrtf(q * (1.f / 128.f) + 1e-5f);
            int row = tt * 64 + wave * 16 + quad * 4 + r;
#pragma unroll
            for (int nt = 0; nt < 8; nt++) {
                float y = fmaxf((acc[tt][nt][r] + blv[nt] - mu) * rstd * gv[nt] + bv[nt], 0.f);
                sh[row * SMS + nt * 16 + ln15] = f2bf16(y);
            }
        }
    }
    __syncthreads();   // also guarantees all global af reads complete before P/Q overwrite

    short8 hf[2][4];
#pragma unroll
    for (int tt = 0; tt < 2; tt++)
#pragma unroll
        for (int kt = 0; kt < 4; kt++)
            hf[tt][kt] = *(const short8*)&sh[(tt * 64 + wave * 16 + ln15) * SMS + kt * 32 + quad * 8];

#pragma unroll
    for (int nt = 0; nt < 8; nt++) {
#pragma unroll
        for (int sel = 0; sel < 2; sel++) {
            floatx4 a0 = {0.f, 0.f, 0.f, 0.f}, a1 = {0.f, 0.f, 0.f, 0.f};
#pragma unroll
            for (int kt = 0; kt < 4; kt++) {
                short8 b = *(const short8*)&W1T[(size_t)(nt * 16 + ln15) * K1 + sel * 128 + kt * 32 + quad * 8];
                a0 = __builtin_amdgcn_mfma_f32_16x16x32_bf16(hf[0][kt], b, a0, 0, 0, 0);
                a1 = __builtin_amdgcn_mfma_f32_16x16x32_bf16(hf[1][kt], b, a1, 0, 0, 0);
            }
            unsigned short* outp = sel ? mean_bf : hbf;
            floatx4 aa[2] = {a0, a1};
#pragma unroll
            for (int tt = 0; tt < 2; tt++) {
#pragma unroll
                for (int r = 0; r < 4; r++) {
                    int node = blkBase + tt * 64 + wave * 16 + quad * 4 + r;
                    if (node < N)
                        outp[(size_t)node * HID + nt * 16 + ln15] = f2bf16(aa[tt][r]);
                }
            }
        }
    }
}

// ---------- edge MLP: wave-autonomous, barrier-free, depth-2 pipelined ----------
// Each wave owns 16-edge groups (strided). All LDS traffic is intra-wave (S round-trip
// only), so no __syncthreads -> no vmcnt drains; next group's gathers stay in flight
// under the current group's 24 MFMAs. Layer 3 is fully in-register (shuffle reduce).
struct ESet {
    int pc, rs, rd;
    short8 ef;
    short8 pf[4];
    short8 qf[4];
};

static __device__ __forceinline__ void emlp_loadidx(const int* __restrict__ csrS,
        const int* __restrict__ csrD, int E, int it, int ln15, ESet& s) {
    int pos = it * 16 + ln15;
    s.pc = pos < E ? pos : E - 1;
    s.rs = csrS[s.pc];
    s.rd = csrD[s.pc];
}

// issue order: ef first, then pf, qf — so the S-MFMA's vmcnt wait (on ef) does not
// drain pf/qf; they keep flying until the z1 phase needs them.
static __device__ __forceinline__ void emlp_gather(const unsigned short* __restrict__ Pbf,
        const unsigned short* __restrict__ Qbf, const unsigned short* __restrict__ eattrP,
        int quad, ESet& s) {
    short8 z = {0, 0, 0, 0, 0, 0, 0, 0};
    s.ef = z;
    const unsigned* ep = (const unsigned*)(eattrP + (size_t)s.pc * 12);
    unsigned* eu = (unsigned*)&s.ef;
    if (quad == 0) {
        eu[0] = ep[0]; eu[1] = ep[1]; eu[2] = ep[2]; eu[3] = ep[3];
    } else if (quad == 1) {
        eu[0] = ep[4]; eu[1] = ep[5];
    }
#pragma unroll
    for (int kt = 0; kt < 4; kt++)
        s.pf[kt] = *(const short8*)&Pbf[(size_t)s.rs * HID + kt * 32 + quad * 8];
#pragma unroll
    for (int kt = 0; kt < 4; kt++)
        s.qf[kt] = *(const short8*)&Qbf[(size_t)s.rd * HID + kt * 32 + quad * 8];
}

static __device__ __forceinline__ void emlp_body(
    unsigned short* __restrict__ sW,
    const unsigned short* __restrict__ W1T, const unsigned short* __restrict__ W2T,
    const int* __restrict__ csrS, const int* __restrict__ csrD, const int* __restrict__ csrE,
    const unsigned short* __restrict__ Pbf, const unsigned short* __restrict__ Qbf,
    const unsigned short* __restrict__ eattrP,
    const float* b1v, const float* b2v, const float* w3v, float b3v,
    float* __restrict__ out, int E, int ln15, int quad, int itCur, int itIdx,
    ESet& cur, ESet& nxt)
{
    // ---- S = eattr @ W1c + b1 (K slice [256,288)) -> per-wave LDS rows ----
#pragma unroll
    for (int nt = 0; nt < 8; nt++) {
        short8 b = *(const short8*)&W1T[(size_t)(nt * 16 + ln15) * K1 + 256 + quad * 8];
        floatx4 sa = {0.f, 0.f, 0.f, 0.f};
        sa = __builtin_amdgcn_mfma_f32_16x16x32_bf16(cur.ef, b, sa, 0, 0, 0);
#pragma unroll
        for (int r = 0; r < 4; r++)
            sW[(quad * 4 + r) * Z1S + nt * 16 + ln15] = f2bf16(sa[r] + b1v[nt]);
    }

    // ---- prefetch: next group's gathers + idx for the group after that ----
    emlp_gather(Pbf, Qbf, eattrP, quad, nxt);
    emlp_loadidx(csrS, csrD, E, itIdx, ln15, cur);   // cur idx regs are free now

    // ---- z1 = relu(P + Q + S), written back into cur.pf (intra-wave LDS read) ----
#pragma unroll
    for (int kt = 0; kt < 4; kt++) {
        short8 s8 = *(const short8*)&sW[ln15 * Z1S + kt * 32 + quad * 8];
#pragma unroll
        for (int w = 0; w < 4; w++) {
            unsigned up = ((unsigned*)&cur.pf[kt])[w];
            unsigned uq = ((unsigned*)&cur.qf[kt])[w];
            unsigned us = ((unsigned*)&s8)[w];
            float lo = bf2f_lo(up) + bf2f_lo(uq) + bf2f_lo(us);
            float hi = bf2f_hi(up) + bf2f_hi(uq) + bf2f_hi(us);
            ((unsigned*)&cur.pf[kt])[w] = pack2bf(fmaxf(lo, 0.f), fmaxf(hi, 0.f));
        }
    }

    // ---- layer 2: [16 x 128] @ [128 x 64] ----
    floatx4 a2[4];
#pragma unroll
    for (int nt = 0; nt < 4; nt++) {
        floatx4 a = {0.f, 0.f, 0.f, 0.f};
#pragma unroll
        for (int kt = 0; kt < 4; kt++) {
            short8 b = *(const short8*)&W2T[(nt * 16 + ln15) * HID + kt * 32 + quad * 8];
            a = __builtin_amdgcn_mfma_f32_16x16x32_bf16(cur.pf[kt], b, a, 0, 0, 0);
        }
        a2[nt] = a;
    }

    // ---- layer 3 + softplus, fully in-register (rows live across 16-lane groups) ----
#pragma unroll
    for (int r = 0; r < 4; r++) {
        float s = 0.f;
#pragma unroll
        for (int nt = 0; nt < 4; nt++)
            s = fmaf(fmaxf(a2[nt][r] + b2v[nt], 0.f), w3v[nt], s);
        s += __shfl_xor(s, 1); s += __shfl_xor(s, 2);
        s += __shfl_xor(s, 4); s += __shfl_xor(s, 8);
        if (ln15 == 0) {
            int p = itCur * 16 + quad * 4 + r;
            if (p < E) {
                float a3 = s + b3v;
                out[csrE[p]] = fmaxf(a3, 0.f) + log1pf(expf(-fabsf(a3)));
            }
        }
    }
}

__global__ __launch_bounds__(256, 3) void edge_mlp_wave(
    const unsigned short* __restrict__ Pbf, const unsigned short* __restrict__ Qbf,
    const int* __restrict__ csrS, const int* __restrict__ csrD, const int* __restrict__ csrE,
    const unsigned short* __restrict__ eattrP,
    const unsigned short* __restrict__ W1T, const float* __restrict__ b1,
    const unsigned short* __restrict__ W2T, const float* __restrict__ b2,
    const float* __restrict__ W3, const float* __restrict__ b3,
    float* __restrict__ out, int E)
{
    __shared__ __align__(16) unsigned short sS[4][16 * Z1S];   // 17408 B, per-wave 16 rows
    const int t = threadIdx.x, wave = t >> 6, lane = t & 63;
    const int ln15 = lane & 15, quad = lane >> 4;
    unsigned short* sW = &sS[wave][0];

    float b1v[8], b2v[4], w3v[4];
#pragma unroll
    for (int nt = 0; nt < 8; nt++) b1v[nt] = b1[nt * 16 + ln15];
#pragma unroll
    for (int nt = 0; nt < 4; nt++) { b2v[nt] = b2[nt * 16 + ln15]; w3v[nt] = W3[nt * 16 + ln15]; }
    const float b3v = b3[0];

    const int G = (E + 15) >> 4;           // 16-edge groups
    const int stride = gridDim.x * 4;      // total waves
    const int gw = blockIdx.x * 4 + wave;

    ESet A, B;
    emlp_loadidx(csrS, csrD, E, gw, ln15, A);
    emlp_gather(Pbf, Qbf, eattrP, quad, A);
    emlp_loadidx(csrS, csrD, E, gw + stride, ln15, B);

    for (int it = gw; it < G; it += 2 * stride) {
        emlp_body(sW, W1T, W2T, csrS, csrD, csrE, Pbf, Qbf, eattrP,
                  b1v, b2v, w3v, b3v, out, E, ln15, quad, it, it + 2 * stride, A, B);
        emlp_body(sW, W1T, W2T, csrS, csrD, csrE, Pbf, Qbf, eattrP,
                  b1v, b2v, w3v, b3v, out, E, ln15, quad, it + stride, it + 3 * stride, B, A);
    }
}

extern "C" void kernel_launch(void* const* d_in, const int* in_sizes, int n_in,
                              void* d_out, int out_size, void* d_ws, size_t ws_size,
                              hipStream_t stream) {
    const float* x       = (const float*)d_in[0];
    const int*   ei      = (const int*)d_in[1];
    const float* eattr   = (const float*)d_in[2];
    const float* node_W  = (const float*)d_in[3];
    const float* node_b  = (const float*)d_in[4];
    const float* sage_Wl = (const float*)d_in[5];
    const float* sage_bl = (const float*)d_in[6];
    const float* sage_Wr = (const float*)d_in[7];
    const float* ln_g    = (const float*)d_in[8];
    const float* ln_b    = (const float*)d_in[9];
    const float* W1 = (const float*)d_in[10];
    const float* b1 = (const float*)d_in[11];
    const float* W2 = (const float*)d_in[12];
    const float* b2 = (const float*)d_in[13];
    const float* W3 = (const float*)d_in[14];
    const float* b3 = (const float*)d_in[15];
    float* out = (float*)d_out;

    const int N = in_sizes[0] / 5;
    const int E = in_sizes[1] / 2;
    const int* src  = ei;
    const int* dstp = ei + E;

    char* ws = (char*)d_ws;
    size_t cur_off = 0;
    auto alloc = [&](size_t bytes) { size_t p = cur_off; cur_off = (cur_off + bytes + 255) & ~(size_t)255; return p; };
    unsigned short* hbf    = (unsigned short*)(ws + alloc((size_t)N * HID * 2));  // h, later P
    unsigned short* meanbf = (unsigned short*)(ws + alloc((size_t)N * HID * 2));  // mean, later Q
    int*            csrS   = (int*)(ws + alloc((size_t)E * 4));
    int*            csrD   = (int*)(ws + alloc((size_t)E * 4));
    int*            csrE   = (int*)(ws + alloc((size_t)E * 4));
    unsigned short* eattrP = (unsigned short*)(ws + alloc((size_t)E * 12 * 2));
    unsigned*       degu   = (unsigned*)(ws + alloc((size_t)N * 4));
    unsigned*       curp   = (unsigned*)(ws + alloc((size_t)N * 4));
    unsigned*       offs   = (unsigned*)(ws + alloc((size_t)N * 4));
    unsigned*       bsum   = (unsigned*)(ws + alloc(64 * 4));
    unsigned short* W1T    = (unsigned short*)(ws + alloc(128 * K1 * 2));
    unsigned short* W2T    = (unsigned short*)(ws + alloc(64 * HID * 2));
    unsigned short* WST    = (unsigned short*)(ws + alloc(3 * 128 * 256 * 2));

    hipMemsetAsync(degu, 0, (size_t)N * sizeof(unsigned), stream);
    hist_kernel<<<(E + 255) / 256, 256, 0, stream>>>(dstp, degu, E);
    int NB = (N + 2047) / 2048;   // 49 for N=100000, fits the 64-lane bsum scan
    scan_partial<<<NB, 256, 0, stream>>>(degu, offs, bsum, N);
    scan_bsum<<<1, 64, 0, stream>>>(bsum, NB);
    scan_add<<<(N + 255) / 256, 256, 0, stream>>>(offs, bsum, curp, N);
    csr_fill<<<(E + 255) / 256, 256, 0, stream>>>(src, dstp, eattr, offs, curp,
                                                  csrS, csrD, csrE, eattrP, E);

    int prepTotal = 128 * K1 + 64 * HID + 3 * 128 * 256;
    prep_weights<<<(prepTotal + 255) / 256, 256, 0, stream>>>(W1, W2, sage_Wl, sage_Wr, W1T, W2T, WST);

    node_proj_kernel<<<(N * 64 + 255) / 256, 256, 0, stream>>>(x, node_W, node_b, hbf, N);

    int nblk = (N + 127) / 128;
    for (int l = 0; l < 2; l++) {
        agg_csr<<<(N + 15) / 16, 256, 0, stream>>>(hbf, csrS, offs, degu, meanbf, N);
        sage_mfma<<<nblk, 256, 0, stream>>>(
            hbf, meanbf, WST + (size_t)l * 128 * 256,
            sage_bl + (size_t)l * HID, ln_g + (size_t)l * HID, ln_b + (size_t)l * HID, N);
    }
    // final layer: fused SAGE + P/Q (P over hbf, Q over meanbf)
    agg_csr<<<(N + 15) / 16, 256, 0, stream>>>(hbf, csrS, offs, degu, meanbf, N);
    sage_pq_mfma<<<nblk, 256, 0, stream>>>(
        hbf, meanbf, WST + (size_t)2 * 128 * 256,
        sage_bl + (size_t)2 * HID, ln_g + (size_t)2 * HID, ln_b + (size_t)2 * HID, W1T, N);

    // wave-autonomous edge MLP: 768 blocks = 3072 waves, ~16 groups/wave, equal strided work
    int G = (E + 15) / 16;
    int nblkE = 768;
    if (nblkE * 4 > G) nblkE = (G + 3) / 4;
    edge_mlp_wave<<<nblkE, 256, 0, stream>>>(
        hbf, meanbf, csrS, csrD, csrE, eattrP, W1T, b1, W2T, b2, W3, b3, out, E);
}